// Round 1
// baseline (166.585 us; speedup 1.0000x reference)
//
#include <hip/hip_runtime.h>

// VisionPooler: 3x3 mean-pool over 48x48 patch grid, x sqrt(768).
// B=16, G=48, D=768, K=3  ->  N=2304 patches, L=256 bins, out [B*L, D] f32
// plus valid_mask [B, L] (all-True) appended flat.

#define B  16
#define G  48
#define D  768
#define NN (G * G)        // 2304
#define LL 256            // output bins per image
#define D4 (D / 4)        // 192 float4 per row

// One block per (b, bin). 192 threads = 3 waves; thread t owns float4 #t of D.
// Each bin = mean of 9 patch rows: 3 groups of 3 consecutive rows.
__global__ __launch_bounds__(192) void pool_kernel(const float* __restrict__ h,
                                                   float* __restrict__ out) {
    const int bl = blockIdx.x;          // 0 .. B*LL-1
    const int b  = bl >> 8;             // bl / 256
    const int l  = bl & 255;            // bl % 256
    const int kx = l & 15;              // bin column (16 bins per grid row)
    const int ky = l >> 4;              // bin row
    const int t  = threadIdx.x;         // 0..191

    const float4* __restrict__ base =
        reinterpret_cast<const float4*>(h) + (size_t)b * NN * D4;

    float4 acc = make_float4(0.f, 0.f, 0.f, 0.f);
#pragma unroll
    for (int r = 0; r < 3; ++r) {
        const int n0 = (3 * ky + r) * G + 3 * kx;   // first of 3 consecutive patches
        const float4* __restrict__ rowp = base + (size_t)n0 * D4 + t;
#pragma unroll
        for (int c = 0; c < 3; ++c) {
            float4 v = rowp[(size_t)c * D4];
            acc.x += v.x; acc.y += v.y; acc.z += v.z; acc.w += v.w;
        }
    }

    const float s = 3.0792014356780038f;   // sqrt(768) / 9
    float4 o = make_float4(acc.x * s, acc.y * s, acc.z * s, acc.w * s);
    reinterpret_cast<float4*>(out)[(size_t)bl * D4 + t] = o;
}

// valid_mask tail: counts==9 everywhere -> all True. Write 1.0f per element
// for however many elements follow the [B*LL, D] block in d_out.
__global__ void mask_kernel(float* __restrict__ out, int n_mask) {
    int i = blockIdx.x * blockDim.x + threadIdx.x;
    if (i < n_mask) out[(size_t)B * LL * D + i] = 1.0f;
}

extern "C" void kernel_launch(void* const* d_in, const int* in_sizes, int n_in,
                              void* d_out, int out_size, void* d_ws, size_t ws_size,
                              hipStream_t stream) {
    const float* h = (const float*)d_in[0];
    float* out = (float*)d_out;

    pool_kernel<<<B * LL, 192, 0, stream>>>(h, out);

    const int n_mask = out_size - B * LL * D;   // expected B*LL = 4096
    if (n_mask > 0) {
        mask_kernel<<<(n_mask + 255) / 256, 256, 0, stream>>>(out, n_mask);
    }
}

// Round 2
// 165.756 us; speedup vs baseline: 1.0050x; 1.0050x over previous
//
#include <hip/hip_runtime.h>

// VisionPooler: 3x3 mean-pool over 48x48 patch grid, x sqrt(768).
// B=16, G=48, D=768, K=3  ->  N=2304 patches, L=256 bins.
// Output: [B*L, D] f32 pooled, then [B*L] valid_mask (all-True -> 1.0f).

#define B  16
#define G  48
#define D  768
#define NN (G * G)           // 2304 patches per image
#define LL 256               // output bins per image
#define D4 (D / 4)           // 192 float4 per row
#define OUT_ELEMS (B * LL * D)

// One block per (b, bin). 192 threads = 3 waves; thread t owns float4 #t of D.
// Each bin = mean of 9 patch rows: 3 groups (r) of 3 consecutive patches (c).
// All 9 loads issued before any arithmetic -> 144 B in flight per thread.
__global__ __launch_bounds__(192) void pool_kernel(const float* __restrict__ h,
                                                   float* __restrict__ out,
                                                   int n_mask) {
    const int bl = blockIdx.x;          // 0 .. B*LL-1
    const int b  = bl >> 8;             // image
    const int l  = bl & 255;            // bin
    const int kx = l & 15;              // bin column (16 per grid row)
    const int ky = l >> 4;              // bin row
    const int t  = threadIdx.x;         // 0..191

    const float4* __restrict__ base =
        reinterpret_cast<const float4*>(h) + (size_t)b * NN * D4 + t;

    // Row starts of the 3 patch rows feeding this bin (each 3 patches contiguous).
    const size_t n0 = (size_t)((3 * ky + 0) * G + 3 * kx) * D4;
    const size_t n1 = (size_t)((3 * ky + 1) * G + 3 * kx) * D4;
    const size_t n2 = (size_t)((3 * ky + 2) * G + 3 * kx) * D4;

    float4 v0 = base[n0];
    float4 v1 = base[n0 + D4];
    float4 v2 = base[n0 + 2 * D4];
    float4 v3 = base[n1];
    float4 v4 = base[n1 + D4];
    float4 v5 = base[n1 + 2 * D4];
    float4 v6 = base[n2];
    float4 v7 = base[n2 + D4];
    float4 v8 = base[n2 + 2 * D4];

    // Tree-sum to shorten the dependency chain.
    float4 s0, s1, s2, s3, acc;
    s0.x = v0.x + v1.x; s0.y = v0.y + v1.y; s0.z = v0.z + v1.z; s0.w = v0.w + v1.w;
    s1.x = v2.x + v3.x; s1.y = v2.y + v3.y; s1.z = v2.z + v3.z; s1.w = v2.w + v3.w;
    s2.x = v4.x + v5.x; s2.y = v4.y + v5.y; s2.z = v4.z + v5.z; s2.w = v4.w + v5.w;
    s3.x = v6.x + v7.x; s3.y = v6.y + v7.y; s3.z = v6.z + v7.z; s3.w = v6.w + v7.w;
    s0.x += s1.x; s0.y += s1.y; s0.z += s1.z; s0.w += s1.w;
    s2.x += s3.x; s2.y += s3.y; s2.z += s3.z; s2.w += s3.w;
    acc.x = s0.x + s2.x + v8.x;
    acc.y = s0.y + s2.y + v8.y;
    acc.z = s0.z + s2.z + v8.z;
    acc.w = s0.w + s2.w + v8.w;

    const float s = 3.0792014356780038f;   // sqrt(768) / 9
    float4 o = make_float4(acc.x * s, acc.y * s, acc.z * s, acc.w * s);
    reinterpret_cast<float4*>(out)[(size_t)bl * D4 + t] = o;

    // Fused valid_mask write: one element per block, all-True by construction.
    if (t == 0 && bl < n_mask) {
        out[(size_t)OUT_ELEMS + bl] = 1.0f;
    }
}

extern "C" void kernel_launch(void* const* d_in, const int* in_sizes, int n_in,
                              void* d_out, int out_size, void* d_ws, size_t ws_size,
                              hipStream_t stream) {
    const float* h = (const float*)d_in[0];
    float* out = (float*)d_out;
    const int n_mask = out_size - OUT_ELEMS;   // expected B*LL = 4096

    pool_kernel<<<B * LL, 192, 0, stream>>>(h, out, n_mask);
}